// Round 1
// baseline (242.264 us; speedup 1.0000x reference)
//
#include <hip/hip_runtime.h>
#include <math.h>

#define NROWS 16384   // B*T
#define DDIM  2048
#define NEXP  16

__device__ __forceinline__ float fnoise(float x) {
    return copysignf(sqrtf(fabsf(x)), x);
}

// ws layout (bytes):
//   [0, 131072)        w_noisy [E][D] float
//   [131072, 131136)   b_noisy [E] float (16 floats + pad)
//   [131136, 131144)   z-loss accumulator (double)

__global__ void prep_kernel(const float* __restrict__ weight,
                            const float* __restrict__ sigma_weight,
                            const float* __restrict__ bias,
                            const float* __restrict__ sigma_bias,
                            const float* __restrict__ eps_in,
                            const float* __restrict__ eps_out,
                            float* __restrict__ w_noisy,
                            float* __restrict__ b_noisy,
                            double* __restrict__ zacc) {
    int idx = blockIdx.x * blockDim.x + threadIdx.x;   // 0 .. E*D-1
    int e = idx >> 11;          // / DDIM
    int d = idx & (DDIM - 1);
    float fi = fnoise(eps_in[d]);
    float fo = fnoise(eps_out[e]);
    w_noisy[idx] = weight[idx] + sigma_weight[idx] * fo * fi;
    if (idx < NEXP) {
        b_noisy[idx] = bias[idx] + sigma_bias[idx] * fnoise(eps_out[idx]);
    }
    if (idx == NEXP) { *zacc = 0.0; }
}

// Block: 256 threads = 4 waves. Block handles 16 rows; wave wv handles rows
// [blockIdx*16 + wv*4, +4). Lanes split D (each lane owns float4 packs).
// Each lane keeps 64 accumulators: acc[r*16+e], partial over its d-subset.
__global__ __launch_bounds__(256) void router_kernel(
        const float* __restrict__ x,        // [NROWS][DDIM]
        const float* __restrict__ w_noisy,  // [E][D]
        const float* __restrict__ b_noisy,  // [E]
        float* __restrict__ out_router,     // [NROWS][E]
        float* __restrict__ out_idx,        // [NROWS][2] stored as float
        double* __restrict__ zacc) {
    __shared__ float wlds[NEXP * 512];      // 32 KiB: chunk [16][512]
    __shared__ float zsh;

    const int tid  = threadIdx.x;
    const int wv   = tid >> 6;
    const int lane = tid & 63;
    if (tid == 0) zsh = 0.0f;

    const int rowBase = blockIdx.x * 16 + wv * 4;
    const float4* xr0 = (const float4*)(x + (size_t)(rowBase + 0) * DDIM);
    const float4* xr1 = (const float4*)(x + (size_t)(rowBase + 1) * DDIM);
    const float4* xr2 = (const float4*)(x + (size_t)(rowBase + 2) * DDIM);
    const float4* xr3 = (const float4*)(x + (size_t)(rowBase + 3) * DDIM);

    float acc[64];
    #pragma unroll
    for (int i = 0; i < 64; ++i) acc[i] = 0.0f;

    const float4* wsrc = (const float4*)w_noisy;  // [16][512] float4
    float4* wdst = (float4*)wlds;                 // [16][128] float4

    for (int c = 0; c < 4; ++c) {
        // stage w chunk c (16 x 512 floats = 2048 float4) cooperatively
        #pragma unroll
        for (int k = 0; k < 8; ++k) {
            int f  = k * 256 + tid;     // 0..2047 flat float4 idx in chunk
            int e  = f >> 7;            // /128
            int dj = f & 127;
            wdst[f] = wsrc[e * 512 + c * 128 + dj];
        }
        __syncthreads();

        #pragma unroll
        for (int k = 0; k < 2; ++k) {
            int p  = c * 128 + k * 64 + lane;   // float4 idx in row
            int dd = k * 64 + lane;             // float4 idx in chunk
            float4 xv0 = xr0[p];
            float4 xv1 = xr1[p];
            float4 xv2 = xr2[p];
            float4 xv3 = xr3[p];
            const float4* wrow = (const float4*)wlds;
            #pragma unroll
            for (int e = 0; e < 16; ++e) {
                float4 w = wrow[e * 128 + dd];
                float s0 = acc[0 * 16 + e];
                float s1 = acc[1 * 16 + e];
                float s2 = acc[2 * 16 + e];
                float s3 = acc[3 * 16 + e];
                s0 = fmaf(xv0.x, w.x, s0); s0 = fmaf(xv0.y, w.y, s0);
                s0 = fmaf(xv0.z, w.z, s0); s0 = fmaf(xv0.w, w.w, s0);
                s1 = fmaf(xv1.x, w.x, s1); s1 = fmaf(xv1.y, w.y, s1);
                s1 = fmaf(xv1.z, w.z, s1); s1 = fmaf(xv1.w, w.w, s1);
                s2 = fmaf(xv2.x, w.x, s2); s2 = fmaf(xv2.y, w.y, s2);
                s2 = fmaf(xv2.z, w.z, s2); s2 = fmaf(xv2.w, w.w, s2);
                s3 = fmaf(xv3.x, w.x, s3); s3 = fmaf(xv3.y, w.y, s3);
                s3 = fmaf(xv3.z, w.z, s3); s3 = fmaf(xv3.w, w.w, s3);
                acc[0 * 16 + e] = s0;
                acc[1 * 16 + e] = s1;
                acc[2 * 16 + e] = s2;
                acc[3 * 16 + e] = s3;
            }
        }
        __syncthreads();
    }

    // Butterfly transpose-reduce: lane l ends with full sum of index l.
    #pragma unroll
    for (int half = 32; half >= 1; half >>= 1) {
        #pragma unroll
        for (int i = 0; i < half; ++i) {
            bool hi = (lane & half) != 0;
            float keep = hi ? acc[i + half] : acc[i];
            float send = hi ? acc[i] : acc[i + half];
            float recv = __shfl_xor(send, half, 64);
            acc[i] = keep + recv;
        }
    }

    const int e = lane & 15;           // expert owned by this lane
    const int r = lane >> 4;           // local row 0..3
    const int row = rowBase + r;
    float logit = acc[0] + b_noisy[e];

    // top-1 with lower-index tie-break within the 16-lane group
    float m1 = logit; int i1 = e;
    #pragma unroll
    for (int off = 8; off >= 1; off >>= 1) {
        float om = __shfl_xor(m1, off, 64);
        int   oi = __shfl_xor(i1, off, 64);
        if (om > m1 || (om == m1 && oi < i1)) { m1 = om; i1 = oi; }
    }
    // top-2: mask out i1
    float v2 = (e == i1) ? -3.4e38f : logit;
    float m2 = v2; int i2 = e;
    #pragma unroll
    for (int off = 8; off >= 1; off >>= 1) {
        float om = __shfl_xor(m2, off, 64);
        int   oi = __shfl_xor(i2, off, 64);
        if (om > m2 || (om == m2 && oi < i2)) { m2 = om; i2 = oi; }
    }

    // softmax over sparse logits: exp(-1e30 - m1) == 0 exactly, so only
    // positions i1, i2 are nonzero.
    float t = expf(m2 - m1);
    float denom = 1.0f + t;
    float p1 = 1.0f / denom;
    float val = (e == i1) ? p1 : ((e == i2) ? t * p1 : 0.0f);
    out_router[(size_t)rowBase * NEXP + lane] = val;   // fully coalesced

    if (e < 2) {
        out_idx[(size_t)row * 2 + e] = (float)((e == 0) ? i1 : i2);
    }

    if (e == 0) {
        float lse = m1 + log1pf(t);
        atomicAdd(&zsh, lse * lse);
    }
    __syncthreads();
    if (tid == 0) {
        atomicAdd(zacc, (double)zsh);
    }
}

__global__ void finalize_kernel(const double* __restrict__ zacc,
                                float* __restrict__ out) {
    if (threadIdx.x == 0 && blockIdx.x == 0) {
        out[NROWS * NEXP + NROWS * 2] = (float)(*zacc * (1.0 / (double)NROWS));
    }
}

extern "C" void kernel_launch(void* const* d_in, const int* in_sizes, int n_in,
                              void* d_out, int out_size, void* d_ws, size_t ws_size,
                              hipStream_t stream) {
    const float* mh      = (const float*)d_in[0];
    const float* weight  = (const float*)d_in[1];
    const float* sigw    = (const float*)d_in[2];
    const float* bias    = (const float*)d_in[3];
    const float* sigb    = (const float*)d_in[4];
    const float* eps_in  = (const float*)d_in[5];
    const float* eps_out = (const float*)d_in[6];

    float* out      = (float*)d_out;
    float* w_noisy  = (float*)d_ws;
    float* b_noisy  = w_noisy + NEXP * DDIM;                          // float idx 32768
    double* zacc    = (double*)((char*)d_ws + NEXP * DDIM * 4 + 64);  // byte 131136

    prep_kernel<<<(NEXP * DDIM) / 256, 256, 0, stream>>>(
        weight, sigw, bias, sigb, eps_in, eps_out, w_noisy, b_noisy, zacc);

    router_kernel<<<NROWS / 16, 256, 0, stream>>>(
        mh, w_noisy, b_noisy, out, out + NROWS * NEXP, zacc);

    finalize_kernel<<<1, 64, 0, stream>>>(zacc, out);
}

// Round 2
// 215.464 us; speedup vs baseline: 1.1244x; 1.1244x over previous
//
#include <hip/hip_runtime.h>
#include <math.h>

#define NROWS 16384   // B*T
#define DDIM  2048
#define NEXP  16
#define RBLOCKS 512   // router grid: 2 blocks/CU on 256 CUs
#define WPB 8         // waves per 512-thread block

__device__ __forceinline__ float fnoise(float x) {
    return copysignf(sqrtf(fabsf(x)), x);
}

// ws layout (float idx):
//   [0, 32768)       w_noisy [E][D]
//   [32768, 32784)   b_noisy [E]
//   [32800, 36896)   zpartial [RBLOCKS*WPB] (one float per wave)

__global__ void prep_kernel(const float* __restrict__ weight,
                            const float* __restrict__ sigma_weight,
                            const float* __restrict__ bias,
                            const float* __restrict__ sigma_bias,
                            const float* __restrict__ eps_in,
                            const float* __restrict__ eps_out,
                            float* __restrict__ w_noisy,
                            float* __restrict__ b_noisy) {
    int idx = blockIdx.x * blockDim.x + threadIdx.x;   // 0 .. E*D-1
    int e = idx >> 11;          // / DDIM
    int d = idx & (DDIM - 1);
    float fi = fnoise(eps_in[d]);
    float fo = fnoise(eps_out[e]);
    w_noisy[idx] = weight[idx] + sigma_weight[idx] * fo * fi;
    if (idx < NEXP) {
        b_noisy[idx] = bias[idx] + sigma_bias[idx] * fnoise(eps_out[idx]);
    }
}

// Block: 512 threads = 8 waves; block handles 32 rows (wave wv: 4 rows).
// w_noisy [16][2048] staged through LDS in 2 chunks of [16][1024] (64 KiB).
// Only 3 barriers per block; grid 512 = 2 blocks/CU so barrier stalls in one
// block overlap compute in the co-resident block.
__global__ __launch_bounds__(512, 4) void router_kernel(
        const float* __restrict__ x,        // [NROWS][DDIM]
        const float* __restrict__ w_noisy,  // [E][D]
        const float* __restrict__ b_noisy,  // [E]
        float* __restrict__ out_router,     // [NROWS][E]
        float* __restrict__ out_idx,        // [NROWS][2] stored as float
        float* __restrict__ zpart) {        // [RBLOCKS*WPB]
    __shared__ float4 wlds[NEXP * 256];     // 64 KiB: chunk [16][256] float4

    const int tid  = threadIdx.x;
    const int wv   = tid >> 6;
    const int lane = tid & 63;

    const int rowBase = blockIdx.x * 32 + wv * 4;
    const float4* xr0 = (const float4*)(x + (size_t)(rowBase + 0) * DDIM);
    const float4* xr1 = (const float4*)(x + (size_t)(rowBase + 1) * DDIM);
    const float4* xr2 = (const float4*)(x + (size_t)(rowBase + 2) * DDIM);
    const float4* xr3 = (const float4*)(x + (size_t)(rowBase + 3) * DDIM);

    float acc[64];
    #pragma unroll
    for (int i = 0; i < 64; ++i) acc[i] = 0.0f;

    const float4* wsrc = (const float4*)w_noisy;  // [16][512] float4

    for (int c = 0; c < 2; ++c) {
        if (c) __syncthreads();   // all waves done reading previous chunk
        // stage chunk c: 16 x 256 float4 = 4096 float4, 8 per thread
        #pragma unroll
        for (int j = 0; j < 8; ++j) {
            int f = j * 512 + tid;              // flat float4 idx in chunk
            wlds[f] = wsrc[(f >> 8) * 512 + c * 256 + (f & 255)];
        }
        __syncthreads();

        #pragma unroll 2
        for (int k = 0; k < 4; ++k) {
            int p  = c * 256 + k * 64 + lane;   // float4 idx in row
            int dd = k * 64 + lane;             // float4 idx in chunk
            float4 xv0 = xr0[p];
            float4 xv1 = xr1[p];
            float4 xv2 = xr2[p];
            float4 xv3 = xr3[p];
            #pragma unroll
            for (int e = 0; e < 16; ++e) {
                float4 w = wlds[e * 256 + dd];
                float s0 = acc[0 * 16 + e];
                float s1 = acc[1 * 16 + e];
                float s2 = acc[2 * 16 + e];
                float s3 = acc[3 * 16 + e];
                s0 = fmaf(xv0.x, w.x, s0); s0 = fmaf(xv0.y, w.y, s0);
                s0 = fmaf(xv0.z, w.z, s0); s0 = fmaf(xv0.w, w.w, s0);
                s1 = fmaf(xv1.x, w.x, s1); s1 = fmaf(xv1.y, w.y, s1);
                s1 = fmaf(xv1.z, w.z, s1); s1 = fmaf(xv1.w, w.w, s1);
                s2 = fmaf(xv2.x, w.x, s2); s2 = fmaf(xv2.y, w.y, s2);
                s2 = fmaf(xv2.z, w.z, s2); s2 = fmaf(xv2.w, w.w, s2);
                s3 = fmaf(xv3.x, w.x, s3); s3 = fmaf(xv3.y, w.y, s3);
                s3 = fmaf(xv3.z, w.z, s3); s3 = fmaf(xv3.w, w.w, s3);
                acc[0 * 16 + e] = s0;
                acc[1 * 16 + e] = s1;
                acc[2 * 16 + e] = s2;
                acc[3 * 16 + e] = s3;
            }
        }
    }

    // Butterfly transpose-reduce: lane l ends with full sum of index l
    // (l = r*16 + e over this wave's 4 rows x 16 experts).
    #pragma unroll
    for (int half = 32; half >= 1; half >>= 1) {
        #pragma unroll
        for (int i = 0; i < half; ++i) {
            bool hi = (lane & half) != 0;
            float keep = hi ? acc[i + half] : acc[i];
            float send = hi ? acc[i] : acc[i + half];
            float recv = __shfl_xor(send, half, 64);
            acc[i] = keep + recv;
        }
    }

    const int e = lane & 15;           // expert owned by this lane
    const int r = lane >> 4;           // local row 0..3
    const int row = rowBase + r;
    float logit = acc[0] + b_noisy[e];

    // top-1 with lower-index tie-break within the 16-lane group
    float m1 = logit; int i1 = e;
    #pragma unroll
    for (int off = 8; off >= 1; off >>= 1) {
        float om = __shfl_xor(m1, off, 64);
        int   oi = __shfl_xor(i1, off, 64);
        if (om > m1 || (om == m1 && oi < i1)) { m1 = om; i1 = oi; }
    }
    // top-2: mask out i1
    float v2 = (e == i1) ? -3.4e38f : logit;
    float m2 = v2; int i2 = e;
    #pragma unroll
    for (int off = 8; off >= 1; off >>= 1) {
        float om = __shfl_xor(m2, off, 64);
        int   oi = __shfl_xor(i2, off, 64);
        if (om > m2 || (om == m2 && oi < i2)) { m2 = om; i2 = oi; }
    }

    // softmax over sparse logits: exp(-1e30 - m1) == 0 exactly, so only
    // positions i1, i2 are nonzero.
    float t = expf(m2 - m1);
    float p1 = 1.0f / (1.0f + t);
    float val = (e == i1) ? p1 : ((e == i2) ? t * p1 : 0.0f);
    out_router[(size_t)rowBase * NEXP + lane] = val;   // fully coalesced

    if (e < 2) {
        out_idx[(size_t)row * 2 + e] = (float)((e == 0) ? i1 : i2);
    }

    // z-loss partial: sum lse^2 over this wave's 4 rows, no atomics.
    float zv = 0.0f;
    if (e == 0) {
        float lse = m1 + log1pf(t);
        zv = lse * lse;
    }
    zv += __shfl_xor(zv, 16, 64);
    zv += __shfl_xor(zv, 32, 64);
    if (lane == 0) {
        zpart[blockIdx.x * WPB + wv] = zv;
    }
}

__global__ void finalize_kernel(const float* __restrict__ zpart,
                                float* __restrict__ out) {
    __shared__ float ws4[4];
    int tid = threadIdx.x;   // 256 threads
    float s = 0.0f;
    for (int i = tid; i < RBLOCKS * WPB; i += 256) s += zpart[i];
    #pragma unroll
    for (int off = 32; off >= 1; off >>= 1) s += __shfl_xor(s, off, 64);
    if ((tid & 63) == 0) ws4[tid >> 6] = s;
    __syncthreads();
    if (tid == 0) {
        float total = ws4[0] + ws4[1] + ws4[2] + ws4[3];
        out[NROWS * NEXP + NROWS * 2] = total * (1.0f / (float)NROWS);
    }
}

extern "C" void kernel_launch(void* const* d_in, const int* in_sizes, int n_in,
                              void* d_out, int out_size, void* d_ws, size_t ws_size,
                              hipStream_t stream) {
    const float* mh      = (const float*)d_in[0];
    const float* weight  = (const float*)d_in[1];
    const float* sigw    = (const float*)d_in[2];
    const float* bias    = (const float*)d_in[3];
    const float* sigb    = (const float*)d_in[4];
    const float* eps_in  = (const float*)d_in[5];
    const float* eps_out = (const float*)d_in[6];

    float* out      = (float*)d_out;
    float* w_noisy  = (float*)d_ws;
    float* b_noisy  = w_noisy + NEXP * DDIM;     // float idx 32768
    float* zpart    = w_noisy + 32800;           // float idx 32800, 128B-aligned

    prep_kernel<<<(NEXP * DDIM) / 256, 256, 0, stream>>>(
        weight, sigw, bias, sigb, eps_in, eps_out, w_noisy, b_noisy);

    router_kernel<<<RBLOCKS, 512, 0, stream>>>(
        mh, w_noisy, b_noisy, out, out + NROWS * NEXP, zpart);

    finalize_kernel<<<1, 256, 0, stream>>>(zpart, out);
}